// Round 1
// baseline (2653.305 us; speedup 1.0000x reference)
//
#include <hip/hip_runtime.h>
#include <hip/hip_cooperative_groups.h>

namespace cg = cooperative_groups;

#define BSZ 1024   // B
#define VSZ 4096   // V
#define NBLK 64    // sinkhorn blocks

// ---------------- softmax(y/2) row-wise, 2048 rows (y_s then y_t) -------------
__global__ __launch_bounds__(256) void softmax_kernel(const float* __restrict__ ys,
                                                      const float* __restrict__ yt,
                                                      float* __restrict__ ps,
                                                      float* __restrict__ pt) {
    int row = blockIdx.x;
    const float* src;
    float* dst;
    if (row < BSZ) { src = ys + (size_t)row * VSZ;        dst = ps + (size_t)row * VSZ; }
    else           { src = yt + (size_t)(row - BSZ) * VSZ; dst = pt + (size_t)(row - BSZ) * VSZ; }
    int t = threadIdx.x;
    float4 v[4];
    float m = -1e30f;
#pragma unroll
    for (int k = 0; k < 4; ++k) {
        v[k] = ((const float4*)src)[t + 256 * k];
        m = fmaxf(m, fmaxf(fmaxf(v[k].x, v[k].y), fmaxf(v[k].z, v[k].w)));
    }
#pragma unroll
    for (int d = 32; d >= 1; d >>= 1) m = fmaxf(m, __shfl_down(m, d));
    __shared__ float sred[4];
    __shared__ float sred2[4];
    int lane = t & 63, wid = t >> 6;
    if (lane == 0) sred[wid] = m;
    __syncthreads();
    m = fmaxf(fmaxf(sred[0], sred[1]), fmaxf(sred[2], sred[3]));
    const float C = 0.7213475204444817f;  // 0.5 * log2(e)  (T = 2)
    float s = 0.f;
#pragma unroll
    for (int k = 0; k < 4; ++k) {
        v[k].x = exp2f((v[k].x - m) * C);
        v[k].y = exp2f((v[k].y - m) * C);
        v[k].z = exp2f((v[k].z - m) * C);
        v[k].w = exp2f((v[k].w - m) * C);
        s += (v[k].x + v[k].y) + (v[k].z + v[k].w);
    }
#pragma unroll
    for (int d = 32; d >= 1; d >>= 1) s += __shfl_down(s, d);
    if (lane == 0) sred2[wid] = s;
    __syncthreads();
    s = (sred2[0] + sred2[1]) + (sred2[2] + sred2[3]);
    float inv = 1.0f / s;
#pragma unroll
    for (int k = 0; k < 4; ++k) {
        v[k].x *= inv; v[k].y *= inv; v[k].z *= inv; v[k].w *= inv;
        ((float4*)dst)[t + 256 * k] = v[k];
    }
}

// ---------------- L1 cdist, transposed output  WT[j][i] = sum_v |pt[j,v]-ps[i,v]|
// grid (16,16,4): x = i-tile (ps rows), y = j-tile (pt rows), z = v-split
#define TS 64
#define BK 32
#define LSTR 36  // 36 floats = 144B, 16B aligned, low bank conflicts

__global__ __launch_bounds__(256, 4) void cdist_kernel(const float* __restrict__ ps,
                                                       const float* __restrict__ pt,
                                                       float* __restrict__ wpart) {
    __shared__ float sP[TS * LSTR];
    __shared__ float sQ[TS * LSTR];
    const int bi = blockIdx.x;
    const int bj = blockIdx.y;
    const int bv = blockIdx.z;
    const int t = threadIdx.x;
    const int cl = t & 15;   // i-lane
    const int rl = t >> 4;   // j-lane (0..15)
    const float* psb = ps + ((size_t)bi * TS) * VSZ + bv * 1024;
    const float* ptb = pt + ((size_t)bj * TS) * VSZ + bv * 1024;
    const int srow0 = t >> 3;        // 0..31
    const int scol = (t & 7) * 4;    // 0..28
    float acc[4][4];
#pragma unroll
    for (int w = 0; w < 4; ++w)
#pragma unroll
        for (int u = 0; u < 4; ++u) acc[w][u] = 0.f;

    for (int kt = 0; kt < 1024; kt += BK) {
        __syncthreads();
#pragma unroll
        for (int h = 0; h < 2; ++h) {
            int row = srow0 + h * 32;
            float4 a = *(const float4*)(psb + (size_t)row * VSZ + kt + scol);
            float4 b = *(const float4*)(ptb + (size_t)row * VSZ + kt + scol);
            *(float4*)(&sP[row * LSTR + scol]) = a;
            *(float4*)(&sQ[row * LSTR + scol]) = b;
        }
        __syncthreads();
#pragma unroll
        for (int vv = 0; vv < BK; vv += 4) {
            float4 pv[4], qv[4];
#pragma unroll
            for (int u = 0; u < 4; ++u) pv[u] = *(const float4*)(&sP[(cl + 16 * u) * LSTR + vv]);
#pragma unroll
            for (int w = 0; w < 4; ++w) qv[w] = *(const float4*)(&sQ[(rl + 16 * w) * LSTR + vv]);
#pragma unroll
            for (int w = 0; w < 4; ++w)
#pragma unroll
                for (int u = 0; u < 4; ++u) {
                    acc[w][u] += (fabsf(pv[u].x - qv[w].x) + fabsf(pv[u].y - qv[w].y)) +
                                 (fabsf(pv[u].z - qv[w].z) + fabsf(pv[u].w - qv[w].w));
                }
        }
    }
    float* outp = wpart + (size_t)bv * (BSZ * BSZ);
#pragma unroll
    for (int w = 0; w < 4; ++w) {
        int jr = bj * TS + rl + 16 * w;
#pragma unroll
        for (int u = 0; u < 4; ++u) {
            int ic = bi * TS + cl + 16 * u;
            outp[(size_t)jr * BSZ + ic] = acc[w][u];
        }
    }
}

// ---------------- combine v-partials, WT = sum, KT = exp(-WT/eps) -------------
__global__ __launch_bounds__(256) void combine_kernel(const float* __restrict__ wpart,
                                                      float* __restrict__ wt,
                                                      float* __restrict__ kt) {
    int idx = blockIdx.x * 256 + threadIdx.x;  // over B*B/4 float4s
    const float4* p0 = (const float4*)wpart;
    const int Q = (BSZ * BSZ) / 4;
    float4 a = p0[idx], b = p0[idx + Q], c = p0[idx + 2 * Q], d = p0[idx + 3 * Q];
    float4 w;
    w.x = (a.x + b.x) + (c.x + d.x);
    w.y = (a.y + b.y) + (c.y + d.y);
    w.z = (a.z + b.z) + (c.z + d.z);
    w.w = (a.w + b.w) + (c.w + d.w);
    ((float4*)wt)[idx] = w;
    const float CE = -14.426950408889634f;  // -log2(e)/eps, eps=0.1
    float4 k;
    k.x = exp2f(w.x * CE);
    k.y = exp2f(w.y * CE);
    k.z = exp2f(w.z * CE);
    k.w = exp2f(w.w * CE);
    ((float4*)kt)[idx] = k;
}

// ---------------- Sinkhorn: a = 1/(K b); b = 1/(K^T a), 20 iters + final sum --
// Block z owns 16 j's (pt index). KT/WT are [j][i] row-major.
__global__ __launch_bounds__(256) void sinkhorn_kernel(const float* __restrict__ KT,
                                                       const float* __restrict__ WT,
                                                       float* __restrict__ cpart,
                                                       float* __restrict__ outpart,
                                                       float* __restrict__ out) {
    cg::grid_group grid = cg::this_grid();
    __shared__ float a_sh[BSZ];
    __shared__ float b_sh[16];
    __shared__ float red[16];
    const int z = blockIdx.x;
    const int t = threadIdx.x;
    if (t < 16) b_sh[t] = 1.0f;
    __syncthreads();
    const int j0 = z * 16;
    for (int it = 0; it < 20; ++it) {
        // phase A: partial c_i = sum_{j in mine} KT[j][i] * b_j   (all i)
        float* cur = cpart + (size_t)(it & 1) * (NBLK * BSZ) + (size_t)z * BSZ;
#pragma unroll
        for (int m2 = 0; m2 < 4; ++m2) {
            int i = t + m2 * 256;
            float s = 0.f;
#pragma unroll
            for (int jj = 0; jj < 16; ++jj)
                s += KT[(size_t)(j0 + jj) * BSZ + i] * b_sh[jj];
            cur[i] = s;
        }
        grid.sync();
        // phase B: a = 1/(full c);  b_j = 1/sum_i KT[j][i] * a_i
        const float* curAll = cpart + (size_t)(it & 1) * (NBLK * BSZ);
#pragma unroll
        for (int m2 = 0; m2 < 4; ++m2) {
            int i = t + m2 * 256;
            float s = 0.f;
            for (int zz = 0; zz < NBLK; ++zz) s += curAll[(size_t)zz * BSZ + i];
            a_sh[i] = 1.0f / s;
        }
        __syncthreads();
        {
            int jj = t >> 4;
            int il = t & 15;
            int j = j0 + jj;
            float s = 0.f;
#pragma unroll 8
            for (int m2 = 0; m2 < 64; ++m2) {
                int i = il + m2 * 16;
                s += KT[(size_t)j * BSZ + i] * a_sh[i];
            }
#pragma unroll
            for (int d = 8; d >= 1; d >>= 1) s += __shfl_down(s, d, 16);
            if (il == 0) b_sh[jj] = 1.0f / s;
        }
        __syncthreads();
    }
    // final: out = 0.001 * sum_{i,j} a_i KT[j][i] b_j WT[j][i]
    {
        int jj = t >> 4;
        int il = t & 15;
        int j = j0 + jj;
        float s = 0.f;
        for (int m2 = 0; m2 < 64; ++m2) {
            int i = il + m2 * 16;
            s += a_sh[i] * KT[(size_t)j * BSZ + i] * WT[(size_t)j * BSZ + i];
        }
#pragma unroll
        for (int d = 8; d >= 1; d >>= 1) s += __shfl_down(s, d, 16);
        if (il == 0) red[jj] = s * b_sh[jj];
        __syncthreads();
        if (t == 0) {
            float ss = 0.f;
#pragma unroll
            for (int q = 0; q < 16; ++q) ss += red[q];
            outpart[z] = ss;
        }
    }
    grid.sync();
    if (z == 0 && t == 0) {
        float ss = 0.f;
        for (int q = 0; q < NBLK; ++q) ss += outpart[q];
        out[0] = 0.001f * ss;
    }
}

extern "C" void kernel_launch(void* const* d_in, const int* in_sizes, int n_in,
                              void* d_out, int out_size, void* d_ws, size_t ws_size,
                              hipStream_t stream) {
    const float* ys = (const float*)d_in[0];
    const float* yt = (const float*)d_in[1];
    float* ws = (float*)d_ws;
    // workspace layout (floats): total ~14.13M floats = ~56.5 MB
    float* ps      = ws;                               // 4M
    float* pt      = ps + (size_t)BSZ * VSZ;           // 4M
    float* wpart   = pt + (size_t)BSZ * VSZ;           // 4 x 1M
    float* wt      = wpart + 4ull * BSZ * BSZ;         // 1M
    float* kt      = wt + (size_t)BSZ * BSZ;           // 1M
    float* cpart   = kt + (size_t)BSZ * BSZ;           // 2*64*1024
    float* outpart = cpart + 2ull * NBLK * BSZ;        // 64
    float* outp    = (float*)d_out;

    softmax_kernel<<<dim3(2 * BSZ), dim3(256), 0, stream>>>(ys, yt, ps, pt);
    cdist_kernel<<<dim3(16, 16, 4), dim3(256), 0, stream>>>(ps, pt, wpart);
    combine_kernel<<<dim3((BSZ * BSZ / 4) / 256), dim3(256), 0, stream>>>(wpart, wt, kt);

    void* args[] = {(void*)&kt, (void*)&wt, (void*)&cpart, (void*)&outpart, (void*)&outp};
    hipLaunchCooperativeKernel((void*)sinkhorn_kernel, dim3(NBLK), dim3(256), args, 0, stream);
}

// Round 2
// 1007.718 us; speedup vs baseline: 2.6330x; 2.6330x over previous
//
#include <hip/hip_runtime.h>
#include <hip/hip_cooperative_groups.h>

namespace cg = cooperative_groups;

#define BSZ 1024   // B
#define VSZ 4096   // V
#define NBLK 64    // sinkhorn blocks

// ---------------- softmax(y/2) row-wise, 2048 rows (y_s then y_t) -------------
__global__ __launch_bounds__(256) void softmax_kernel(const float* __restrict__ ys,
                                                      const float* __restrict__ yt,
                                                      float* __restrict__ ps,
                                                      float* __restrict__ pt) {
    int row = blockIdx.x;
    const float* src;
    float* dst;
    if (row < BSZ) { src = ys + (size_t)row * VSZ;        dst = ps + (size_t)row * VSZ; }
    else           { src = yt + (size_t)(row - BSZ) * VSZ; dst = pt + (size_t)(row - BSZ) * VSZ; }
    int t = threadIdx.x;
    float4 v[4];
    float m = -1e30f;
#pragma unroll
    for (int k = 0; k < 4; ++k) {
        v[k] = ((const float4*)src)[t + 256 * k];
        m = fmaxf(m, fmaxf(fmaxf(v[k].x, v[k].y), fmaxf(v[k].z, v[k].w)));
    }
#pragma unroll
    for (int d = 32; d >= 1; d >>= 1) m = fmaxf(m, __shfl_down(m, d));
    __shared__ float sred[4];
    __shared__ float sred2[4];
    int lane = t & 63, wid = t >> 6;
    if (lane == 0) sred[wid] = m;
    __syncthreads();
    m = fmaxf(fmaxf(sred[0], sred[1]), fmaxf(sred[2], sred[3]));
    const float C = 0.7213475204444817f;  // 0.5 * log2(e)  (T = 2)
    float s = 0.f;
#pragma unroll
    for (int k = 0; k < 4; ++k) {
        v[k].x = exp2f((v[k].x - m) * C);
        v[k].y = exp2f((v[k].y - m) * C);
        v[k].z = exp2f((v[k].z - m) * C);
        v[k].w = exp2f((v[k].w - m) * C);
        s += (v[k].x + v[k].y) + (v[k].z + v[k].w);
    }
#pragma unroll
    for (int d = 32; d >= 1; d >>= 1) s += __shfl_down(s, d);
    if (lane == 0) sred2[wid] = s;
    __syncthreads();
    s = (sred2[0] + sred2[1]) + (sred2[2] + sred2[3]);
    float inv = 1.0f / s;
#pragma unroll
    for (int k = 0; k < 4; ++k) {
        v[k].x *= inv; v[k].y *= inv; v[k].z *= inv; v[k].w *= inv;
        ((float4*)dst)[t + 256 * k] = v[k];
    }
}

// ---------------- L1 cdist, transposed output  WT[j][i] = sum_v |pt[j,v]-ps[i,v]|
// grid (16,16,4): x = i-tile (ps rows), y = j-tile (pt rows), z = v-split
#define TS 64
#define BK 32
#define LSTR 36  // 36 floats = 144B, 16B aligned, low bank conflicts

// NOTE: no second launch_bounds arg — with (256,4) the allocator capped at 64
// VGPRs and spilled the 16-accumulator tile to scratch (R1: 6 GB HBM writes).
__global__ __launch_bounds__(256) void cdist_kernel(const float* __restrict__ ps,
                                                    const float* __restrict__ pt,
                                                    float* __restrict__ wpart) {
    __shared__ float sP[TS * LSTR];
    __shared__ float sQ[TS * LSTR];
    const int bi = blockIdx.x;
    const int bj = blockIdx.y;
    const int bv = blockIdx.z;
    const int t = threadIdx.x;
    const int cl = t & 15;   // i-lane
    const int rl = t >> 4;   // j-lane (0..15)
    const float* psb = ps + ((size_t)bi * TS) * VSZ + bv * 1024;
    const float* ptb = pt + ((size_t)bj * TS) * VSZ + bv * 1024;
    const int srow0 = t >> 3;        // 0..31
    const int scol = (t & 7) * 4;    // 0..28

    float a00 = 0.f, a01 = 0.f, a02 = 0.f, a03 = 0.f;
    float a10 = 0.f, a11 = 0.f, a12 = 0.f, a13 = 0.f;
    float a20 = 0.f, a21 = 0.f, a22 = 0.f, a23 = 0.f;
    float a30 = 0.f, a31 = 0.f, a32 = 0.f, a33 = 0.f;

    for (int kt = 0; kt < 1024; kt += BK) {
        __syncthreads();
#pragma unroll
        for (int h = 0; h < 2; ++h) {
            int row = srow0 + h * 32;
            float4 a = *(const float4*)(psb + (size_t)row * VSZ + kt + scol);
            float4 b = *(const float4*)(ptb + (size_t)row * VSZ + kt + scol);
            *(float4*)(&sP[row * LSTR + scol]) = a;
            *(float4*)(&sQ[row * LSTR + scol]) = b;
        }
        __syncthreads();
#pragma unroll
        for (int vv = 0; vv < BK; vv += 4) {
            float4 p0 = *(const float4*)(&sP[(cl +  0) * LSTR + vv]);
            float4 p1 = *(const float4*)(&sP[(cl + 16) * LSTR + vv]);
            float4 p2 = *(const float4*)(&sP[(cl + 32) * LSTR + vv]);
            float4 p3 = *(const float4*)(&sP[(cl + 48) * LSTR + vv]);
            float4 q0 = *(const float4*)(&sQ[(rl +  0) * LSTR + vv]);
            float4 q1 = *(const float4*)(&sQ[(rl + 16) * LSTR + vv]);
            float4 q2 = *(const float4*)(&sQ[(rl + 32) * LSTR + vv]);
            float4 q3 = *(const float4*)(&sQ[(rl + 48) * LSTR + vv]);
#define L1ACC(ACC, P, Q)                                                      \
    ACC += (fabsf(P.x - Q.x) + fabsf(P.y - Q.y)) +                            \
           (fabsf(P.z - Q.z) + fabsf(P.w - Q.w));
            L1ACC(a00, p0, q0) L1ACC(a01, p1, q0) L1ACC(a02, p2, q0) L1ACC(a03, p3, q0)
            L1ACC(a10, p0, q1) L1ACC(a11, p1, q1) L1ACC(a12, p2, q1) L1ACC(a13, p3, q1)
            L1ACC(a20, p0, q2) L1ACC(a21, p1, q2) L1ACC(a22, p2, q2) L1ACC(a23, p3, q2)
            L1ACC(a30, p0, q3) L1ACC(a31, p1, q3) L1ACC(a32, p2, q3) L1ACC(a33, p3, q3)
#undef L1ACC
        }
    }
    float* outp = wpart + (size_t)bv * (BSZ * BSZ);
    float accs[4][4] = {{a00, a01, a02, a03},
                        {a10, a11, a12, a13},
                        {a20, a21, a22, a23},
                        {a30, a31, a32, a33}};
#pragma unroll
    for (int w = 0; w < 4; ++w) {
        int jr = bj * TS + rl + 16 * w;
#pragma unroll
        for (int u = 0; u < 4; ++u) {
            int ic = bi * TS + cl + 16 * u;
            outp[(size_t)jr * BSZ + ic] = accs[w][u];
        }
    }
}

// ---------------- combine v-partials, WT = sum, KT = exp(-WT/eps) -------------
__global__ __launch_bounds__(256) void combine_kernel(const float* __restrict__ wpart,
                                                      float* __restrict__ wt,
                                                      float* __restrict__ kt) {
    int idx = blockIdx.x * 256 + threadIdx.x;  // over B*B/4 float4s
    const float4* p0 = (const float4*)wpart;
    const int Q = (BSZ * BSZ) / 4;
    float4 a = p0[idx], b = p0[idx + Q], c = p0[idx + 2 * Q], d = p0[idx + 3 * Q];
    float4 w;
    w.x = (a.x + b.x) + (c.x + d.x);
    w.y = (a.y + b.y) + (c.y + d.y);
    w.z = (a.z + b.z) + (c.z + d.z);
    w.w = (a.w + b.w) + (c.w + d.w);
    ((float4*)wt)[idx] = w;
    const float CE = -14.426950408889634f;  // -log2(e)/eps, eps=0.1
    float4 k;
    k.x = exp2f(w.x * CE);
    k.y = exp2f(w.y * CE);
    k.z = exp2f(w.z * CE);
    k.w = exp2f(w.w * CE);
    ((float4*)kt)[idx] = k;
}

// ---------------- Sinkhorn: a = 1/(K b); b = 1/(K^T a), 20 iters + final sum --
// Block z owns 16 j's (pt index). KT/WT are [j][i] row-major.
__global__ __launch_bounds__(256) void sinkhorn_kernel(const float* __restrict__ KT,
                                                       const float* __restrict__ WT,
                                                       float* __restrict__ cpart,
                                                       float* __restrict__ outpart,
                                                       float* __restrict__ out) {
    cg::grid_group grid = cg::this_grid();
    __shared__ float a_sh[BSZ];
    __shared__ float b_sh[16];
    __shared__ float red[16];
    const int z = blockIdx.x;
    const int t = threadIdx.x;
    if (t < 16) b_sh[t] = 1.0f;
    __syncthreads();
    const int j0 = z * 16;
    for (int it = 0; it < 20; ++it) {
        // phase A: partial c_i = sum_{j in mine} KT[j][i] * b_j   (all i)
        float* cur = cpart + (size_t)(it & 1) * (NBLK * BSZ) + (size_t)z * BSZ;
#pragma unroll
        for (int m2 = 0; m2 < 4; ++m2) {
            int i = t + m2 * 256;
            float s = 0.f;
#pragma unroll
            for (int jj = 0; jj < 16; ++jj)
                s += KT[(size_t)(j0 + jj) * BSZ + i] * b_sh[jj];
            cur[i] = s;
        }
        grid.sync();
        // phase B: a = 1/(full c);  b_j = 1/sum_i KT[j][i] * a_i
        const float* curAll = cpart + (size_t)(it & 1) * (NBLK * BSZ);
#pragma unroll
        for (int m2 = 0; m2 < 4; ++m2) {
            int i = t + m2 * 256;
            float s = 0.f;
            for (int zz = 0; zz < NBLK; ++zz) s += curAll[(size_t)zz * BSZ + i];
            a_sh[i] = 1.0f / s;
        }
        __syncthreads();
        {
            int jj = t >> 4;
            int il = t & 15;
            int j = j0 + jj;
            float s = 0.f;
#pragma unroll 8
            for (int m2 = 0; m2 < 64; ++m2) {
                int i = il + m2 * 16;
                s += KT[(size_t)j * BSZ + i] * a_sh[i];
            }
#pragma unroll
            for (int d = 8; d >= 1; d >>= 1) s += __shfl_down(s, d, 16);
            if (il == 0) b_sh[jj] = 1.0f / s;
        }
        __syncthreads();
    }
    // final: out = 0.001 * sum_{i,j} a_i KT[j][i] b_j WT[j][i]
    {
        int jj = t >> 4;
        int il = t & 15;
        int j = j0 + jj;
        float s = 0.f;
        for (int m2 = 0; m2 < 64; ++m2) {
            int i = il + m2 * 16;
            s += a_sh[i] * KT[(size_t)j * BSZ + i] * WT[(size_t)j * BSZ + i];
        }
#pragma unroll
        for (int d = 8; d >= 1; d >>= 1) s += __shfl_down(s, d, 16);
        if (il == 0) red[jj] = s * b_sh[jj];
        __syncthreads();
        if (t == 0) {
            float ss = 0.f;
#pragma unroll
            for (int q = 0; q < 16; ++q) ss += red[q];
            outpart[z] = ss;
        }
    }
    grid.sync();
    if (z == 0 && t == 0) {
        float ss = 0.f;
        for (int q = 0; q < NBLK; ++q) ss += outpart[q];
        out[0] = 0.001f * ss;
    }
}

extern "C" void kernel_launch(void* const* d_in, const int* in_sizes, int n_in,
                              void* d_out, int out_size, void* d_ws, size_t ws_size,
                              hipStream_t stream) {
    const float* ys = (const float*)d_in[0];
    const float* yt = (const float*)d_in[1];
    float* ws = (float*)d_ws;
    // workspace layout (floats): total ~14.13M floats = ~56.5 MB
    float* ps      = ws;                               // 4M
    float* pt      = ps + (size_t)BSZ * VSZ;           // 4M
    float* wpart   = pt + (size_t)BSZ * VSZ;           // 4 x 1M
    float* wt      = wpart + 4ull * BSZ * BSZ;         // 1M
    float* kt      = wt + (size_t)BSZ * BSZ;           // 1M
    float* cpart   = kt + (size_t)BSZ * BSZ;           // 2*64*1024
    float* outpart = cpart + 2ull * NBLK * BSZ;        // 64
    float* outp    = (float*)d_out;

    softmax_kernel<<<dim3(2 * BSZ), dim3(256), 0, stream>>>(ys, yt, ps, pt);
    cdist_kernel<<<dim3(16, 16, 4), dim3(256), 0, stream>>>(ps, pt, wpart);
    combine_kernel<<<dim3((BSZ * BSZ / 4) / 256), dim3(256), 0, stream>>>(wpart, wt, kt);

    void* args[] = {(void*)&kt, (void*)&wt, (void*)&cpart, (void*)&outpart, (void*)&outp};
    hipLaunchCooperativeKernel((void*)sinkhorn_kernel, dim3(NBLK), dim3(256), args, 0, stream);
}

// Round 4
// 891.295 us; speedup vs baseline: 2.9769x; 1.1306x over previous
//
#include <hip/hip_runtime.h>
#include <hip/hip_fp16.h>

#define BSZ 1024   // B
#define VSZ 4096   // V
#define NBLK 64    // sinkhorn blocks

typedef _Float16 h2 __attribute__((ext_vector_type(2)));
union F4H { float4 f; h2 h[4]; };

#if defined(__has_builtin) && __has_builtin(__builtin_elementwise_min)
#define H2MIN(a, b) __builtin_elementwise_min((a), (b))
#else
static __device__ inline h2 H2MIN(h2 a, h2 b) {
    h2 r; r[0] = a[0] < b[0] ? a[0] : b[0]; r[1] = a[1] < b[1] ? a[1] : b[1]; return r;
}
#endif

#if defined(__has_builtin) && __has_builtin(__builtin_amdgcn_fdot2)
#define DOT2ACC(m, acc) acc = __builtin_amdgcn_fdot2((m), (h2){(_Float16)1.0f, (_Float16)1.0f}, (acc), false)
#else
#define DOT2ACC(m, acc) acc += (float)(m)[0] + (float)(m)[1]
#endif

// ---------------- softmax(y/2) row-wise, writes f16 probs ---------------------
__global__ __launch_bounds__(256) void softmax_kernel(const float* __restrict__ ys,
                                                      const float* __restrict__ yt,
                                                      __half* __restrict__ ps,
                                                      __half* __restrict__ pt) {
    int row = blockIdx.x;
    const float* src;
    __half* dst;
    if (row < BSZ) { src = ys + (size_t)row * VSZ;         dst = ps + (size_t)row * VSZ; }
    else           { src = yt + (size_t)(row - BSZ) * VSZ; dst = pt + (size_t)(row - BSZ) * VSZ; }
    int t = threadIdx.x;
    float4 v[4];
    float m = -1e30f;
#pragma unroll
    for (int k = 0; k < 4; ++k) {
        v[k] = ((const float4*)src)[t + 256 * k];
        m = fmaxf(m, fmaxf(fmaxf(v[k].x, v[k].y), fmaxf(v[k].z, v[k].w)));
    }
#pragma unroll
    for (int d = 32; d >= 1; d >>= 1) m = fmaxf(m, __shfl_down(m, d));
    __shared__ float sred[4];
    __shared__ float sred2[4];
    int lane = t & 63, wid = t >> 6;
    if (lane == 0) sred[wid] = m;
    __syncthreads();
    m = fmaxf(fmaxf(sred[0], sred[1]), fmaxf(sred[2], sred[3]));
    const float C = 0.7213475204444817f;  // 0.5 * log2(e)  (T = 2)
    float s = 0.f;
#pragma unroll
    for (int k = 0; k < 4; ++k) {
        v[k].x = exp2f((v[k].x - m) * C);
        v[k].y = exp2f((v[k].y - m) * C);
        v[k].z = exp2f((v[k].z - m) * C);
        v[k].w = exp2f((v[k].w - m) * C);
        s += (v[k].x + v[k].y) + (v[k].z + v[k].w);
    }
#pragma unroll
    for (int d = 32; d >= 1; d >>= 1) s += __shfl_down(s, d);
    if (lane == 0) sred2[wid] = s;
    __syncthreads();
    s = (sred2[0] + sred2[1]) + (sred2[2] + sred2[3]);
    float inv = 1.0f / s;
#pragma unroll
    for (int k = 0; k < 4; ++k) {
        union { __half h[4]; uint2 u; } o;
        o.h[0] = __float2half(v[k].x * inv);
        o.h[1] = __float2half(v[k].y * inv);
        o.h[2] = __float2half(v[k].z * inv);
        o.h[3] = __float2half(v[k].w * inv);
        ((uint2*)dst)[t + 256 * k] = o.u;
    }
}

// ---------------- S-partial: ST[j][i] = sum_v min(ps[i,v], pt[j,v])  ----------
// W = 2 - 2*S (softmax rows sum to 1). grid (16,16,4): x=i-tile, y=j-tile, z=v.
#define TS 64
#define LSTRH 72  // f16 row stride (144 B): banks alias 2-way -> free (m136)

__global__ __launch_bounds__(256) void cdist_kernel(const __half* __restrict__ psh,
                                                    const __half* __restrict__ pth,
                                                    float* __restrict__ spart) {
    __shared__ __half sP[2][TS * LSTRH];
    __shared__ __half sQ[2][TS * LSTRH];
    const int bi = blockIdx.x;
    const int bj = blockIdx.y;
    const int bv = blockIdx.z;
    const int t = threadIdx.x;
    const int cl = t & 15;   // i-lane
    const int rl = t >> 4;   // j-lane
    const __half* psb = psh + ((size_t)bi * TS) * VSZ + bv * 1024;
    const __half* ptb = pth + ((size_t)bj * TS) * VSZ + bv * 1024;
    // staging: threads 0..127 load P (64 rows x 64 halfs/tile), 128..255 load Q.
    // Each thread: 64 contiguous bytes = 4 float4s.  (R3 bug: only 1 float4.)
    const int isP = (t < 128);
    const int lt = t & 127;
    const int srow = lt >> 1;            // 0..63
    const int sc0 = (lt & 1) * 32;       // half-offset: 0 or 32
    const __half* gsrc = (isP ? psb : ptb) + (size_t)srow * VSZ + sc0;
    __half* lbase0 = (isP ? sP[0] : sQ[0]) + srow * LSTRH + sc0;
    __half* lbase1 = (isP ? sP[1] : sQ[1]) + srow * LSTRH + sc0;

    float a00 = 0.f, a01 = 0.f, a02 = 0.f, a03 = 0.f;
    float a10 = 0.f, a11 = 0.f, a12 = 0.f, a13 = 0.f;
    float a20 = 0.f, a21 = 0.f, a22 = 0.f, a23 = 0.f;
    float a30 = 0.f, a31 = 0.f, a32 = 0.f, a33 = 0.f;

    // prologue: stage tile 0 fully into buf 0
    {
        float4 r0 = *(const float4*)(gsrc + 0);
        float4 r1 = *(const float4*)(gsrc + 8);
        float4 r2 = *(const float4*)(gsrc + 16);
        float4 r3 = *(const float4*)(gsrc + 24);
        *(float4*)(lbase0 + 0)  = r0;
        *(float4*)(lbase0 + 8)  = r1;
        *(float4*)(lbase0 + 16) = r2;
        *(float4*)(lbase0 + 24) = r3;
    }
    __syncthreads();

    for (int kt = 0; kt < 16; ++kt) {
        const int cur = kt & 1;
        float4 rn0, rn1, rn2, rn3;
        if (kt < 15) {  // prefetch tile kt+1 (64 halfs further along v)
            const __half* g = gsrc + (kt + 1) * 64;
            rn0 = *(const float4*)(g + 0);
            rn1 = *(const float4*)(g + 8);
            rn2 = *(const float4*)(g + 16);
            rn3 = *(const float4*)(g + 24);
        }
        const __half* pbase = sP[cur] + cl * LSTRH;
        const __half* qbase = sQ[cur] + rl * LSTRH;
#pragma unroll
        for (int vv = 0; vv < 8; ++vv) {
            F4H p0, p1, p2, p3, q0, q1, q2, q3;
            p0.f = *(const float4*)(pbase + 0 * 16 * LSTRH + vv * 8);
            p1.f = *(const float4*)(pbase + 1 * 16 * LSTRH + vv * 8);
            p2.f = *(const float4*)(pbase + 2 * 16 * LSTRH + vv * 8);
            p3.f = *(const float4*)(pbase + 3 * 16 * LSTRH + vv * 8);
            q0.f = *(const float4*)(qbase + 0 * 16 * LSTRH + vv * 8);
            q1.f = *(const float4*)(qbase + 1 * 16 * LSTRH + vv * 8);
            q2.f = *(const float4*)(qbase + 2 * 16 * LSTRH + vv * 8);
            q3.f = *(const float4*)(qbase + 3 * 16 * LSTRH + vv * 8);
#define MINACC(A, P, Q)                                   \
    { h2 m0_ = H2MIN(P.h[0], Q.h[0]); DOT2ACC(m0_, A);    \
      h2 m1_ = H2MIN(P.h[1], Q.h[1]); DOT2ACC(m1_, A);    \
      h2 m2_ = H2MIN(P.h[2], Q.h[2]); DOT2ACC(m2_, A);    \
      h2 m3_ = H2MIN(P.h[3], Q.h[3]); DOT2ACC(m3_, A); }
            MINACC(a00, p0, q0) MINACC(a01, p1, q0) MINACC(a02, p2, q0) MINACC(a03, p3, q0)
            MINACC(a10, p0, q1) MINACC(a11, p1, q1) MINACC(a12, p2, q1) MINACC(a13, p3, q1)
            MINACC(a20, p0, q2) MINACC(a21, p1, q2) MINACC(a22, p2, q2) MINACC(a23, p3, q2)
            MINACC(a30, p0, q3) MINACC(a31, p1, q3) MINACC(a32, p2, q3) MINACC(a33, p3, q3)
#undef MINACC
        }
        if (kt < 15) {  // write tile kt+1 into the other buffer
            __half* lb = cur ? lbase0 : lbase1;
            *(float4*)(lb + 0)  = rn0;
            *(float4*)(lb + 8)  = rn1;
            *(float4*)(lb + 16) = rn2;
            *(float4*)(lb + 24) = rn3;
        }
        __syncthreads();
    }

    float* outp = spart + (size_t)bv * (BSZ * BSZ);
    float accs[4][4] = {{a00, a01, a02, a03},
                        {a10, a11, a12, a13},
                        {a20, a21, a22, a23},
                        {a30, a31, a32, a33}};
#pragma unroll
    for (int w = 0; w < 4; ++w) {
        int jr = bj * TS + rl + 16 * w;
#pragma unroll
        for (int u = 0; u < 4; ++u) {
            int ic = bi * TS + cl + 16 * u;
            outp[(size_t)jr * BSZ + ic] = accs[w][u];
        }
    }
}

// ------- combine v-partials: W = 2 - 2*S, K = exp(-W/eps); also init barrier --
__global__ __launch_bounds__(256) void combine_kernel(const float* __restrict__ spart,
                                                      float* __restrict__ wt,
                                                      float* __restrict__ kt,
                                                      unsigned* __restrict__ bar) {
    if (blockIdx.x == 0 && threadIdx.x == 0) { bar[0] = 0u; bar[1] = 0u; }
    int idx = blockIdx.x * 256 + threadIdx.x;  // over B*B/4 float4s
    const float4* p0 = (const float4*)spart;
    const int Q = (BSZ * BSZ) / 4;
    float4 a = p0[idx], b = p0[idx + Q], c = p0[idx + 2 * Q], d = p0[idx + 3 * Q];
    float4 w;
    w.x = 2.0f - 2.0f * ((a.x + b.x) + (c.x + d.x));
    w.y = 2.0f - 2.0f * ((a.y + b.y) + (c.y + d.y));
    w.z = 2.0f - 2.0f * ((a.z + b.z) + (c.z + d.z));
    w.w = 2.0f - 2.0f * ((a.w + b.w) + (c.w + d.w));
    ((float4*)wt)[idx] = w;
    const float CE = -14.426950408889634f;  // -log2(e)/eps, eps=0.1
    float4 k;
    k.x = exp2f(w.x * CE);
    k.y = exp2f(w.y * CE);
    k.z = exp2f(w.z * CE);
    k.w = exp2f(w.w * CE);
    ((float4*)kt)[idx] = k;
}

// ------- hand-rolled grid barrier; ALL threads fence (release+acquire/L1-inv) -
__device__ inline void grid_barrier(unsigned* bar) {
    __threadfence();   // release: each thread's own global stores -> device scope
    __syncthreads();
    if (threadIdx.x == 0) {
        unsigned g = __hip_atomic_load(&bar[1], __ATOMIC_RELAXED, __HIP_MEMORY_SCOPE_AGENT);
        unsigned old = __hip_atomic_fetch_add(&bar[0], 1u, __ATOMIC_ACQ_REL, __HIP_MEMORY_SCOPE_AGENT);
        if (old == NBLK - 1) {
            __hip_atomic_store(&bar[0], 0u, __ATOMIC_RELAXED, __HIP_MEMORY_SCOPE_AGENT);
            __hip_atomic_fetch_add(&bar[1], 1u, __ATOMIC_RELEASE, __HIP_MEMORY_SCOPE_AGENT);
        } else {
            while (__hip_atomic_load(&bar[1], __ATOMIC_ACQUIRE, __HIP_MEMORY_SCOPE_AGENT) == g)
                __builtin_amdgcn_s_sleep(1);
        }
    }
    __syncthreads();
    __threadfence();   // acquire: invalidate stale L1 lines before re-reading cpart
}

// ---------------- Sinkhorn: a = 1/(K b); b = 1/(K^T a), 20 iters + final sum --
__global__ __launch_bounds__(256) void sinkhorn_kernel(const float* __restrict__ KT,
                                                       const float* __restrict__ WT,
                                                       float* __restrict__ cpart,
                                                       float* __restrict__ outpart,
                                                       float* __restrict__ out,
                                                       unsigned* __restrict__ bar) {
    __shared__ __align__(16) float a_sh[BSZ];
    __shared__ float b_sh[16];
    __shared__ float red[16];
    const int z = blockIdx.x;
    const int t = threadIdx.x;
    if (t < 16) b_sh[t] = 1.0f;
    __syncthreads();
    const int j0 = z * 16;
    const int jj = t >> 4;
    const int il = t & 15;
    const float4* krow = (const float4*)(KT + (size_t)(j0 + jj) * BSZ);
    for (int it = 0; it < 20; ++it) {
        // phase A: partial c = sum over my 16 j's of K[i,j]*b_j, vectorized over i
        float4* cur = (float4*)(cpart + (size_t)(it & 1) * (NBLK * BSZ) + (size_t)z * BSZ);
        float4 s = {0.f, 0.f, 0.f, 0.f};
#pragma unroll
        for (int q = 0; q < 16; ++q) {
            float4 kv = ((const float4*)(KT + (size_t)(j0 + q) * BSZ))[t];
            float bb = b_sh[q];
            s.x += kv.x * bb; s.y += kv.y * bb; s.z += kv.z * bb; s.w += kv.w * bb;
        }
        cur[t] = s;
        grid_barrier(bar);
        // phase B: a = 1/(sum of all partials); b_j = 1/sum_i K[i,j] a_i
        const float4* curAll = (const float4*)(cpart + (size_t)(it & 1) * (NBLK * BSZ));
        float4 c = {0.f, 0.f, 0.f, 0.f};
        for (int zz = 0; zz < NBLK; ++zz) {
            float4 v = curAll[zz * 256 + t];
            c.x += v.x; c.y += v.y; c.z += v.z; c.w += v.w;
        }
        float4 ar;
        ar.x = 1.0f / c.x; ar.y = 1.0f / c.y; ar.z = 1.0f / c.z; ar.w = 1.0f / c.w;
        ((float4*)a_sh)[t] = ar;
        __syncthreads();
        float sb = 0.f;
#pragma unroll
        for (int m2 = 0; m2 < 16; ++m2) {
            float4 kv = krow[il + 16 * m2];
            float4 av = ((const float4*)a_sh)[il + 16 * m2];
            sb += (kv.x * av.x + kv.y * av.y) + (kv.z * av.z + kv.w * av.w);
        }
#pragma unroll
        for (int d = 8; d >= 1; d >>= 1) sb += __shfl_down(sb, d, 16);
        if (il == 0) b_sh[jj] = 1.0f / sb;
        __syncthreads();
    }
    // final: out = 0.001 * sum_{i,j} a_i K[i,j] b_j W[i,j]
    {
        const float4* wrow = (const float4*)(WT + (size_t)(j0 + jj) * BSZ);
        float sb = 0.f;
#pragma unroll 4
        for (int m2 = 0; m2 < 16; ++m2) {
            float4 kv = krow[il + 16 * m2];
            float4 wv = wrow[il + 16 * m2];
            float4 av = ((const float4*)a_sh)[il + 16 * m2];
            sb += (av.x * kv.x * wv.x + av.y * kv.y * wv.y) +
                  (av.z * kv.z * wv.z + av.w * kv.w * wv.w);
        }
#pragma unroll
        for (int d = 8; d >= 1; d >>= 1) sb += __shfl_down(sb, d, 16);
        if (il == 0) red[jj] = sb * b_sh[jj];
        __syncthreads();
        if (t == 0) {
            float ss = 0.f;
#pragma unroll
            for (int q = 0; q < 16; ++q) ss += red[q];
            outpart[z] = ss;
        }
    }
    grid_barrier(bar);
    if (z == 0 && t == 0) {
        float ss = 0.f;
        for (int q = 0; q < NBLK; ++q) ss += outpart[q];
        out[0] = 0.001f * ss;
    }
}

extern "C" void kernel_launch(void* const* d_in, const int* in_sizes, int n_in,
                              void* d_out, int out_size, void* d_ws, size_t ws_size,
                              hipStream_t stream) {
    const float* ys = (const float*)d_in[0];
    const float* yt = (const float*)d_in[1];
    float* ws = (float*)d_ws;
    // workspace layout (float units): ~10.3M floats = ~41 MB
    __half* psh    = (__half*)ws;                          // 4M halfs = 2M floats
    __half* pth    = (__half*)(ws + 2ull * 1024 * 1024);   // 2M floats
    float* spart   = ws + 4ull * 1024 * 1024;              // 4 x 1M
    float* wt      = spart + 4ull * BSZ * BSZ;             // 1M
    float* kt      = wt + (size_t)BSZ * BSZ;               // 1M
    float* cpart   = kt + (size_t)BSZ * BSZ;               // 2*64*1024
    float* outpart = cpart + 2ull * NBLK * BSZ;            // 64
    unsigned* bar  = (unsigned*)(outpart + 64);            // 2
    float* outp    = (float*)d_out;

    softmax_kernel<<<dim3(2 * BSZ), dim3(256), 0, stream>>>(ys, yt, psh, pth);
    cdist_kernel<<<dim3(16, 16, 4), dim3(256), 0, stream>>>(psh, pth, spart);
    combine_kernel<<<dim3((BSZ * BSZ / 4) / 256), dim3(256), 0, stream>>>(spart, wt, kt, bar);

    void* args[] = {(void*)&kt, (void*)&wt, (void*)&cpart, (void*)&outpart, (void*)&outp, (void*)&bar};
    hipLaunchCooperativeKernel((void*)sinkhorn_kernel, dim3(NBLK), dim3(256), args, 0, stream);
}

// Round 5
// 516.635 us; speedup vs baseline: 5.1357x; 1.7252x over previous
//
#include <hip/hip_runtime.h>
#include <hip/hip_fp16.h>

#define BSZ 1024   // B
#define VSZ 4096   // V
#define NBLK 64    // sinkhorn blocks
#define KPAD 1040  // LDS row stride for K (1024 + 16 floats)

typedef _Float16 h2 __attribute__((ext_vector_type(2)));
union F4H { float4 f; h2 h[4]; };

#if defined(__has_builtin) && __has_builtin(__builtin_elementwise_min)
#define H2MIN(a, b) __builtin_elementwise_min((a), (b))
#else
static __device__ inline h2 H2MIN(h2 a, h2 b) {
    h2 r; r[0] = a[0] < b[0] ? a[0] : b[0]; r[1] = a[1] < b[1] ? a[1] : b[1]; return r;
}
#endif

#if defined(__has_builtin) && __has_builtin(__builtin_amdgcn_fdot2)
#define DOT2ACC(m, acc) acc = __builtin_amdgcn_fdot2((m), (h2){(_Float16)1.0f, (_Float16)1.0f}, (acc), false)
#else
#define DOT2ACC(m, acc) acc += (float)(m)[0] + (float)(m)[1]
#endif

// ---------------- softmax(y/2) row-wise, writes f16 probs ---------------------
__global__ __launch_bounds__(256) void softmax_kernel(const float* __restrict__ ys,
                                                      const float* __restrict__ yt,
                                                      __half* __restrict__ ps,
                                                      __half* __restrict__ pt) {
    int row = blockIdx.x;
    const float* src;
    __half* dst;
    if (row < BSZ) { src = ys + (size_t)row * VSZ;         dst = ps + (size_t)row * VSZ; }
    else           { src = yt + (size_t)(row - BSZ) * VSZ; dst = pt + (size_t)(row - BSZ) * VSZ; }
    int t = threadIdx.x;
    float4 v[4];
    float m = -1e30f;
#pragma unroll
    for (int k = 0; k < 4; ++k) {
        v[k] = ((const float4*)src)[t + 256 * k];
        m = fmaxf(m, fmaxf(fmaxf(v[k].x, v[k].y), fmaxf(v[k].z, v[k].w)));
    }
#pragma unroll
    for (int d = 32; d >= 1; d >>= 1) m = fmaxf(m, __shfl_down(m, d));
    __shared__ float sred[4];
    __shared__ float sred2[4];
    int lane = t & 63, wid = t >> 6;
    if (lane == 0) sred[wid] = m;
    __syncthreads();
    m = fmaxf(fmaxf(sred[0], sred[1]), fmaxf(sred[2], sred[3]));
    const float C = 0.7213475204444817f;  // 0.5 * log2(e)  (T = 2)
    float s = 0.f;
#pragma unroll
    for (int k = 0; k < 4; ++k) {
        v[k].x = exp2f((v[k].x - m) * C);
        v[k].y = exp2f((v[k].y - m) * C);
        v[k].z = exp2f((v[k].z - m) * C);
        v[k].w = exp2f((v[k].w - m) * C);
        s += (v[k].x + v[k].y) + (v[k].z + v[k].w);
    }
#pragma unroll
    for (int d = 32; d >= 1; d >>= 1) s += __shfl_down(s, d);
    if (lane == 0) sred2[wid] = s;
    __syncthreads();
    s = (sred2[0] + sred2[1]) + (sred2[2] + sred2[3]);
    float inv = 1.0f / s;
#pragma unroll
    for (int k = 0; k < 4; ++k) {
        union { __half h[4]; uint2 u; } o;
        o.h[0] = __float2half(v[k].x * inv);
        o.h[1] = __float2half(v[k].y * inv);
        o.h[2] = __float2half(v[k].z * inv);
        o.h[3] = __float2half(v[k].w * inv);
        ((uint2*)dst)[t + 256 * k] = o.u;
    }
}

// ---------------- S-partial: ST[j][i] = sum_v min(ps[i,v], pt[j,v])  ----------
// W = 2 - 2*S (softmax rows sum to 1). grid (16,16,4): x=i-tile, y=j-tile, z=v.
#define TS 64
#define LSTRH 72  // f16 row stride (144 B): banks alias 2-way -> free (m136)

__global__ __launch_bounds__(256) void cdist_kernel(const __half* __restrict__ psh,
                                                    const __half* __restrict__ pth,
                                                    float* __restrict__ spart) {
    __shared__ __half sP[2][TS * LSTRH];
    __shared__ __half sQ[2][TS * LSTRH];
    const int bi = blockIdx.x;
    const int bj = blockIdx.y;
    const int bv = blockIdx.z;
    const int t = threadIdx.x;
    const int cl = t & 15;   // i-lane
    const int rl = t >> 4;   // j-lane
    const __half* psb = psh + ((size_t)bi * TS) * VSZ + bv * 1024;
    const __half* ptb = pth + ((size_t)bj * TS) * VSZ + bv * 1024;
    // staging: threads 0..127 load P (64 rows x 64 halfs/tile), 128..255 load Q.
    const int isP = (t < 128);
    const int lt = t & 127;
    const int srow = lt >> 1;            // 0..63
    const int sc0 = (lt & 1) * 32;       // half-offset: 0 or 32
    const __half* gsrc = (isP ? psb : ptb) + (size_t)srow * VSZ + sc0;
    __half* lbase0 = (isP ? sP[0] : sQ[0]) + srow * LSTRH + sc0;
    __half* lbase1 = (isP ? sP[1] : sQ[1]) + srow * LSTRH + sc0;

    float a00 = 0.f, a01 = 0.f, a02 = 0.f, a03 = 0.f;
    float a10 = 0.f, a11 = 0.f, a12 = 0.f, a13 = 0.f;
    float a20 = 0.f, a21 = 0.f, a22 = 0.f, a23 = 0.f;
    float a30 = 0.f, a31 = 0.f, a32 = 0.f, a33 = 0.f;

    // prologue: stage tile 0 fully into buf 0
    {
        float4 r0 = *(const float4*)(gsrc + 0);
        float4 r1 = *(const float4*)(gsrc + 8);
        float4 r2 = *(const float4*)(gsrc + 16);
        float4 r3 = *(const float4*)(gsrc + 24);
        *(float4*)(lbase0 + 0)  = r0;
        *(float4*)(lbase0 + 8)  = r1;
        *(float4*)(lbase0 + 16) = r2;
        *(float4*)(lbase0 + 24) = r3;
    }
    __syncthreads();

    for (int kt = 0; kt < 16; ++kt) {
        const int cur = kt & 1;
        float4 rn0, rn1, rn2, rn3;
        if (kt < 15) {  // prefetch tile kt+1 (64 halfs further along v)
            const __half* g = gsrc + (kt + 1) * 64;
            rn0 = *(const float4*)(g + 0);
            rn1 = *(const float4*)(g + 8);
            rn2 = *(const float4*)(g + 16);
            rn3 = *(const float4*)(g + 24);
        }
        const __half* pbase = sP[cur] + cl * LSTRH;
        const __half* qbase = sQ[cur] + rl * LSTRH;
#pragma unroll
        for (int vv = 0; vv < 8; ++vv) {
            F4H p0, p1, p2, p3, q0, q1, q2, q3;
            p0.f = *(const float4*)(pbase + 0 * 16 * LSTRH + vv * 8);
            p1.f = *(const float4*)(pbase + 1 * 16 * LSTRH + vv * 8);
            p2.f = *(const float4*)(pbase + 2 * 16 * LSTRH + vv * 8);
            p3.f = *(const float4*)(pbase + 3 * 16 * LSTRH + vv * 8);
            q0.f = *(const float4*)(qbase + 0 * 16 * LSTRH + vv * 8);
            q1.f = *(const float4*)(qbase + 1 * 16 * LSTRH + vv * 8);
            q2.f = *(const float4*)(qbase + 2 * 16 * LSTRH + vv * 8);
            q3.f = *(const float4*)(qbase + 3 * 16 * LSTRH + vv * 8);
#define MINACC(A, P, Q)                                   \
    { h2 m0_ = H2MIN(P.h[0], Q.h[0]); DOT2ACC(m0_, A);    \
      h2 m1_ = H2MIN(P.h[1], Q.h[1]); DOT2ACC(m1_, A);    \
      h2 m2_ = H2MIN(P.h[2], Q.h[2]); DOT2ACC(m2_, A);    \
      h2 m3_ = H2MIN(P.h[3], Q.h[3]); DOT2ACC(m3_, A); }
            MINACC(a00, p0, q0) MINACC(a01, p1, q0) MINACC(a02, p2, q0) MINACC(a03, p3, q0)
            MINACC(a10, p0, q1) MINACC(a11, p1, q1) MINACC(a12, p2, q1) MINACC(a13, p3, q1)
            MINACC(a20, p0, q2) MINACC(a21, p1, q2) MINACC(a22, p2, q2) MINACC(a23, p3, q2)
            MINACC(a30, p0, q3) MINACC(a31, p1, q3) MINACC(a32, p2, q3) MINACC(a33, p3, q3)
#undef MINACC
        }
        if (kt < 15) {  // write tile kt+1 into the other buffer
            __half* lb = cur ? lbase0 : lbase1;
            *(float4*)(lb + 0)  = rn0;
            *(float4*)(lb + 8)  = rn1;
            *(float4*)(lb + 16) = rn2;
            *(float4*)(lb + 24) = rn3;
        }
        __syncthreads();
    }

    float* outp = spart + (size_t)bv * (BSZ * BSZ);
    float accs[4][4] = {{a00, a01, a02, a03},
                        {a10, a11, a12, a13},
                        {a20, a21, a22, a23},
                        {a30, a31, a32, a33}};
#pragma unroll
    for (int w = 0; w < 4; ++w) {
        int jr = bj * TS + rl + 16 * w;
#pragma unroll
        for (int u = 0; u < 4; ++u) {
            int ic = bi * TS + cl + 16 * u;
            outp[(size_t)jr * BSZ + ic] = accs[w][u];
        }
    }
}

// ------- combine v-partials: W = 2 - 2*S, K = exp(-W/eps); also init barrier --
__global__ __launch_bounds__(256) void combine_kernel(const float* __restrict__ spart,
                                                      float* __restrict__ wt,
                                                      float* __restrict__ kt,
                                                      unsigned* __restrict__ bar) {
    if (blockIdx.x == 0 && threadIdx.x == 0) { bar[0] = 0u; bar[1] = 0u; }
    int idx = blockIdx.x * 256 + threadIdx.x;  // over B*B/4 float4s
    const float4* p0 = (const float4*)spart;
    const int Q = (BSZ * BSZ) / 4;
    float4 a = p0[idx], b = p0[idx + Q], c = p0[idx + 2 * Q], d = p0[idx + 3 * Q];
    float4 w;
    w.x = 2.0f - 2.0f * ((a.x + b.x) + (c.x + d.x));
    w.y = 2.0f - 2.0f * ((a.y + b.y) + (c.y + d.y));
    w.z = 2.0f - 2.0f * ((a.z + b.z) + (c.z + d.z));
    w.w = 2.0f - 2.0f * ((a.w + b.w) + (c.w + d.w));
    ((float4*)wt)[idx] = w;
    const float CE = -14.426950408889634f;  // -log2(e)/eps, eps=0.1
    float4 k;
    k.x = exp2f(w.x * CE);
    k.y = exp2f(w.y * CE);
    k.z = exp2f(w.z * CE);
    k.w = exp2f(w.w * CE);
    ((float4*)kt)[idx] = k;
}

// ------- grid barrier: RELAXED polling (no per-poll cache inv), thread-0 fences
// R4 post-mortem: ACQUIRE in the poll loop emitted buffer_inv per poll from 63
// blocks -> continuous L2 nuking, K refetched from HBM every iter (FETCH 22MB),
// 28us/barrier. RELAXED agent loads still read the coherence point (sc1) so
// visibility is preserved; exactly one acquire after poll exit.
__device__ inline void grid_barrier(unsigned* bar) {
    __syncthreads();   // compiler drains vmcnt before s_barrier -> stores complete
    if (threadIdx.x == 0) {
        unsigned g = __hip_atomic_load(&bar[1], __ATOMIC_RELAXED, __HIP_MEMORY_SCOPE_AGENT);
        // ACQ_REL: release flushes this block's cpart stores (wbl2); the LAST
        // arriver's acquire (inv) makes all blocks' stores visible to it.
        unsigned old = __hip_atomic_fetch_add(&bar[0], 1u, __ATOMIC_ACQ_REL, __HIP_MEMORY_SCOPE_AGENT);
        if (old == NBLK - 1) {
            __hip_atomic_store(&bar[0], 0u, __ATOMIC_RELAXED, __HIP_MEMORY_SCOPE_AGENT);
            // RELEASE waits vmcnt(0): bar[0] reset is visible before wakeup.
            __hip_atomic_store(&bar[1], g + 1u, __ATOMIC_RELEASE, __HIP_MEMORY_SCOPE_AGENT);
        } else {
            while (__hip_atomic_load(&bar[1], __ATOMIC_RELAXED, __HIP_MEMORY_SCOPE_AGENT) == g)
                __builtin_amdgcn_s_sleep(2);
            // single acquire: one L1/L2 inv for the whole block (L1 is per-CU).
            (void)__hip_atomic_load(&bar[1], __ATOMIC_ACQUIRE, __HIP_MEMORY_SCOPE_AGENT);
        }
    }
    __syncthreads();
}

// ---------------- Sinkhorn: a = 1/(K b); b = 1/(K^T a), 20 iters + final sum --
// Block z owns 16 j's; its 16 K rows live in LDS (immune to the barrier's L2
// invalidates). Only cpart (4 KB/block/iter) crosses the grid.
__global__ __launch_bounds__(256) void sinkhorn_kernel(const float* __restrict__ KT,
                                                       const float* __restrict__ WT,
                                                       float* __restrict__ cpart,
                                                       float* __restrict__ outpart,
                                                       float* __restrict__ out,
                                                       unsigned* __restrict__ bar) {
    __shared__ __align__(16) float k_lds[16 * KPAD];
    __shared__ __align__(16) float a_sh[BSZ];
    __shared__ float b_sh[16];
    __shared__ float red[16];
    const int z = blockIdx.x;
    const int t = threadIdx.x;
    const int j0 = z * 16;
    // stage my 16 K rows: 256 threads x 1 float4 per row
#pragma unroll 4
    for (int r = 0; r < 16; ++r) {
        float4 v = ((const float4*)(KT + (size_t)(j0 + r) * BSZ))[t];
        *(float4*)(&k_lds[r * KPAD + t * 4]) = v;
    }
    if (t < 16) b_sh[t] = 1.0f;
    __syncthreads();
    const int jj = t >> 4;
    const int il = t & 15;
    for (int it = 0; it < 20; ++it) {
        // phase A: partial c = sum over my 16 j's of K[i,j]*b_j (K from LDS)
        float4* cur = (float4*)(cpart + (size_t)(it & 1) * (NBLK * BSZ) + (size_t)z * BSZ);
        float4 s = {0.f, 0.f, 0.f, 0.f};
#pragma unroll
        for (int q = 0; q < 16; ++q) {
            float4 kv = *(const float4*)(&k_lds[q * KPAD + t * 4]);
            float bb = b_sh[q];
            s.x += kv.x * bb; s.y += kv.y * bb; s.z += kv.z * bb; s.w += kv.w * bb;
        }
        cur[t] = s;
        grid_barrier(bar);
        // phase B: a = 1/(sum of all partials); b_j = 1/sum_i K[i,j] a_i
        const float4* curAll = (const float4*)(cpart + (size_t)(it & 1) * (NBLK * BSZ));
        float4 c = {0.f, 0.f, 0.f, 0.f};
        for (int zz = 0; zz < NBLK; ++zz) {
            float4 v = curAll[zz * 256 + t];
            c.x += v.x; c.y += v.y; c.z += v.z; c.w += v.w;
        }
        float4 ar;
        ar.x = 1.0f / c.x; ar.y = 1.0f / c.y; ar.z = 1.0f / c.z; ar.w = 1.0f / c.w;
        ((float4*)a_sh)[t] = ar;
        __syncthreads();
        float sb = 0.f;
#pragma unroll
        for (int m2 = 0; m2 < 16; ++m2) {
            float4 kv = *(const float4*)(&k_lds[jj * KPAD + (il + 16 * m2) * 4]);
            float4 av = ((const float4*)a_sh)[il + 16 * m2];
            sb += (kv.x * av.x + kv.y * av.y) + (kv.z * av.z + kv.w * av.w);
        }
#pragma unroll
        for (int d = 8; d >= 1; d >>= 1) sb += __shfl_down(sb, d, 16);
        if (il == 0) b_sh[jj] = 1.0f / sb;
        __syncthreads();
    }
    // final: out = 0.001 * sum_{i,j} a_i K[i,j] b_j W[i,j]
    {
        const float4* wrow = (const float4*)(WT + (size_t)(j0 + jj) * BSZ);
        float sb = 0.f;
#pragma unroll 4
        for (int m2 = 0; m2 < 16; ++m2) {
            float4 kv = *(const float4*)(&k_lds[jj * KPAD + (il + 16 * m2) * 4]);
            float4 wv = wrow[il + 16 * m2];
            float4 av = ((const float4*)a_sh)[il + 16 * m2];
            sb += (av.x * kv.x * wv.x + av.y * kv.y * wv.y) +
                  (av.z * kv.z * wv.z + av.w * kv.w * wv.w);
        }
#pragma unroll
        for (int d = 8; d >= 1; d >>= 1) sb += __shfl_down(sb, d, 16);
        if (il == 0) red[jj] = sb * b_sh[jj];
        __syncthreads();
        if (t == 0) {
            float ss = 0.f;
#pragma unroll
            for (int q = 0; q < 16; ++q) ss += red[q];
            outpart[z] = ss;
        }
    }
    grid_barrier(bar);
    if (z == 0 && t == 0) {
        float ss = 0.f;
        for (int q = 0; q < NBLK; ++q) ss += outpart[q];
        out[0] = 0.001f * ss;
    }
}

extern "C" void kernel_launch(void* const* d_in, const int* in_sizes, int n_in,
                              void* d_out, int out_size, void* d_ws, size_t ws_size,
                              hipStream_t stream) {
    const float* ys = (const float*)d_in[0];
    const float* yt = (const float*)d_in[1];
    float* ws = (float*)d_ws;
    // workspace layout (float units): ~10.3M floats = ~41 MB
    __half* psh    = (__half*)ws;                          // 4M halfs = 2M floats
    __half* pth    = (__half*)(ws + 2ull * 1024 * 1024);   // 2M floats
    float* spart   = ws + 4ull * 1024 * 1024;              // 4 x 1M
    float* wt      = spart + 4ull * BSZ * BSZ;             // 1M
    float* kt      = wt + (size_t)BSZ * BSZ;               // 1M
    float* cpart   = kt + (size_t)BSZ * BSZ;               // 2*64*1024
    float* outpart = cpart + 2ull * NBLK * BSZ;            // 64
    unsigned* bar  = (unsigned*)(outpart + 96);            // own 128B line
    float* outp    = (float*)d_out;

    softmax_kernel<<<dim3(2 * BSZ), dim3(256), 0, stream>>>(ys, yt, psh, pth);
    cdist_kernel<<<dim3(16, 16, 4), dim3(256), 0, stream>>>(psh, pth, spart);
    combine_kernel<<<dim3((BSZ * BSZ / 4) / 256), dim3(256), 0, stream>>>(spart, wt, kt, bar);

    void* args[] = {(void*)&kt, (void*)&wt, (void*)&cpart, (void*)&outpart, (void*)&outp, (void*)&bar};
    hipLaunchCooperativeKernel((void*)sinkhorn_kernel, dim3(NBLK), dim3(256), args, 0, stream);
}